// Round 22
// baseline (404.910 us; speedup 1.0000x reference)
//
#include <hip/hip_runtime.h>
#include <hip/hip_bf16.h>

#define NN 50000
#define NE 1600000
#define BUCKET 128   // aw slots per node; degree ~ Poisson(32), max ~70 << 128

typedef float f32x4 __attribute__((ext_vector_type(4)));
typedef short bf16x8 __attribute__((ext_vector_type(8)));
typedef __fp16 f16x2 __attribute__((ext_vector_type(2)));
typedef unsigned short u16;

// bf16 convert via HIP intrinsic (RNE).
__device__ inline u16 f2bf(float f) {
    union { __hip_bfloat16 h; u16 u; } c;
    c.h = __float2bfloat16(f);
    return c.u;
}
__device__ inline float bf2f(u16 u) {
    union { unsigned u; float f; } v; v.u = ((unsigned)u) << 16; return v.f;
}
__device__ inline void pack8v(bf16x8& d, f32x4 p0, f32x4 p1) {
    d[0]=(short)f2bf(p0[0]); d[1]=(short)f2bf(p0[1]); d[2]=(short)f2bf(p0[2]); d[3]=(short)f2bf(p0[3]);
    d[4]=(short)f2bf(p1[0]); d[5]=(short)f2bf(p1[1]); d[6]=(short)f2bf(p1[2]); d[7]=(short)f2bf(p1[3]);
}
// nt for streamed-once data only (attr, edge_out, node_out, x).
__device__ inline f32x4 ntload4(const float* p) {
    return __builtin_nontemporal_load((const f32x4*)p);
}

// ---------------------------------------------------------------------------
// K0: fold weights.
// ---------------------------------------------------------------------------
#define PREP_TOT (128*384 + 384 + 64*160 + 160)

__global__ void k_prep(const float* __restrict__ Wl, const float* __restrict__ bl,
                       const float* __restrict__ We, const float* __restrict__ be,
                       const float* __restrict__ W_att, const float* __restrict__ b_att,
                       const float* __restrict__ W_eout, const float* __restrict__ b_eout,
                       float* __restrict__ WC1, float* __restrict__ BC1,
                       float* __restrict__ WC2, float* __restrict__ BC2) {
    int id = blockIdx.x * blockDim.x + threadIdx.x;
    if (id < 128*384) {
        int k = id / 384, col = id % 384;
        float v;
        if (col < 128) v = Wl[k*128 + col];
        else {
            int role = (col - 128) >> 7;          // 0 = u_i(dst), 1 = u_j(src)
            int hc = (col - 128) & 127, h = hc >> 6, a = hc & 63;
            float s = 0.f;
            for (int c = 0; c < 64; c++) s += Wl[k*128 + h*64 + c] * W_att[(role*64 + c)*64 + a];
            v = s;
        }
        WC1[id] = v;
    } else if (id < 128*384 + 384) {
        int col = id - 128*384;
        float v;
        if (col < 128) v = bl[col];
        else {
            int role = (col - 128) >> 7;
            int hc = (col - 128) & 127, h = hc >> 6, a = hc & 63;
            float s = 0.f;
            for (int c = 0; c < 64; c++) s += bl[h*64 + c] * W_att[(role*64 + c)*64 + a];
            v = s;
        }
        BC1[col] = v;
    } else if (id < 128*384 + 384 + 64*160) {
        int id2 = id - (128*384 + 384);
        int k = id2 / 160, col = id2 % 160;
        float s = 0.f;
        if (col < 32) { for (int m = 0; m < 64; m++) s += We[k*64 + m] * W_eout[m*32 + col]; }
        else {
            int hc = col - 32, h = hc >> 6, a = hc & 63;
            for (int j = 0; j < 32; j++) s += We[k*64 + h*32 + j] * W_att[(128 + j)*64 + a];
        }
        WC2[id2] = s;
    } else if (id < PREP_TOT) {
        int col = id - (128*384 + 384 + 64*160);
        float s = 0.f;
        if (col < 32) { for (int m = 0; m < 64; m++) s += be[m] * W_eout[m*32 + col]; s += b_eout[col]; }
        else {
            int hc = col - 32, h = hc >> 6, a = hc & 63;
            for (int j = 0; j < 32; j++) s += be[h*32 + j] * W_att[(128 + j)*64 + a];
            s += b_att[a];
        }
        BC2[col] = s;
    }
}

// K0b: pre-pack WC2 into per-lane bf16 MFMA B-fragments.
__global__ void k_prep2(const float* __restrict__ WC2, u16* __restrict__ WC2b) {
    int id = blockIdx.x * blockDim.x + threadIdx.x;
    if (id < 10240) {
        int j = id & 7, l = (id >> 3) & 63, ks = (id >> 9) & 1, t = id >> 10;
        int col = t*16 + (l & 15);
        int k = ks*32 + (l >> 4)*8 + j;
        WC2b[id] = f2bf(WC2[k*160 + col]);
    }
}

// ---------------------------------------------------------------------------
// K1: node transform -> XL[N,128] bf16 (xl) and UU[N,256] bf16 (u_i|u_j).
// ---------------------------------------------------------------------------
__global__ __launch_bounds__(256) void k_node(const float* __restrict__ x,
                                              const float* __restrict__ WC1,
                                              const float* __restrict__ BC1,
                                              u16* __restrict__ XL,
                                              u16* __restrict__ UU) {
    const int w = threadIdx.x >> 6, l = threadIdx.x & 63;
    const int l15 = l & 15, lhi = l >> 4;

    bf16x8 B[6][4];
    #pragma unroll
    for (int t = 0; t < 6; t++) {
        int col = (6*w + t)*16 + l15;
        #pragma unroll
        for (int ks = 0; ks < 4; ks++) {
            #pragma unroll
            for (int j = 0; j < 8; j++) {
                int k = ks*32 + lhi*8 + j;
                B[t][ks][j] = (short)f2bf(WC1[k*384 + col]);
            }
        }
    }

    for (int nb = blockIdx.x * 16; nb < NN; nb += gridDim.x * 16) {
        int row = nb + l15;
        bf16x8 A[4];
        #pragma unroll
        for (int ks = 0; ks < 4; ks++) {
            const float* p = x + (size_t)row*128 + ks*32 + lhi*8;
            pack8v(A[ks], ntload4(p), ntload4(p + 4));
        }
        #pragma unroll
        for (int t = 0; t < 6; t++) {
            f32x4 acc = {0.f, 0.f, 0.f, 0.f};
            #pragma unroll
            for (int ks = 0; ks < 4; ks++)
                acc = __builtin_amdgcn_mfma_f32_16x16x32_bf16(A[ks], B[t][ks], acc, 0, 0, 0);
            int col = (6*w + t)*16 + l15;
            float bias = BC1[col];
            #pragma unroll
            for (int r = 0; r < 4; r++) {
                int node = nb + lhi*4 + r;
                float v = acc[r] + bias;
                if (col < 128) XL[(size_t)node*128 + col] = f2bf(v);
                else           UU[(size_t)node*256 + (col - 128)] = f2bf(v);
            }
        }
    }
}

// ---------------------------------------------------------------------------
// K2: wave-autonomous edge kernel, HALF-ROTATED attr pipeline:
//   ar00/01 rotated mid-loop (8 VGPR live across MFMA+phase2);
//   ar10/11 issued at END of iter i for iter i+1 — they die at pack A[1]
//   BEFORE the MFMA block, so peak pressure during MFMA drops ~8 VGPR vs
//   full rotation (R19: 104 VGPR = 4 waves/SIMD; target <=102 = 5 waves).
// Grid 5120 divides evenly under BOTH capacities (5*1024 / 4*1280) — the
// VGPR gamble cannot reintroduce R20's ragged-tail loss.
// NOTE: plain launch_bounds(256) — min-waves bound spills B (R6).
// ---------------------------------------------------------------------------
__global__ __launch_bounds__(256) void k_edge(const float* __restrict__ attr,
                                              const int* __restrict__ ei,
                                              const u16* __restrict__ UU,
                                              const u16* __restrict__ WC2b,
                                              const float* __restrict__ BC2,
                                              const float* __restrict__ att,
                                              float* __restrict__ edge_out,
                                              int* __restrict__ curs,
                                              int2* __restrict__ aw) {
    __shared__ u16 vlds[4][16 * 136];
    const int tid = threadIdx.x;
    const int w = tid >> 6, l = tid & 63, l15 = l & 15, lhi = l >> 4;

    bf16x8 B[10][2];
    #pragma unroll
    for (int t = 0; t < 10; t++)
        #pragma unroll
        for (int ks = 0; ks < 2; ks++)
            B[t][ks] = *(const bf16x8*)(WC2b + (size_t)((t*2 + ks)*64 + l)*8);

    // per-lane attention weights for chunk c=l15 (head = c>>3)
    float att_c[8];
    {
        int base = (l15 >> 3)*64 + (l15 & 7)*8;
        f32x4 t0 = *(const f32x4*)(att + base);
        f32x4 t1 = *(const f32x4*)(att + base + 4);
        att_c[0]=t0[0]; att_c[1]=t0[1]; att_c[2]=t0[2]; att_c[3]=t0[3];
        att_c[4]=t1[0]; att_c[5]=t1[1]; att_c[6]=t1[2]; att_c[7]=t1[3];
    }

    u16* vw = vlds[w];
    const int STRIDE = gridDim.x * 64;
    int e0 = (blockIdx.x*4 + w)*16;
    int srcP = 0, dstP = 0;
    if (l < 16) { srcP = ei[e0 + l]; dstP = ei[NE + e0 + l]; }
    // prologue: prefetch iter-0 attr (both halves)
    f32x4 ar00, ar01, ar10, ar11;
    {
        const float* pa = attr + (size_t)(e0 + l15)*64 + lhi*8;
        ar00 = ntload4(pa); ar01 = ntload4(pa + 4);
        ar10 = ntload4(pa + 32); ar11 = ntload4(pa + 36);
    }

    for (; e0 < NE; e0 += STRIDE) {
        // --- bucket slot (result consumed in phase 2) ---
        int posP = 0;
        if (l < 16) posP = atomicAdd(curs + dstP, 1);

        // --- coalesced UU gathers: lane = (edge 4q+lhi, chunk l15); CACHED ---
        bf16x8 ug[4], vg[4];
        #pragma unroll
        for (int q = 0; q < 4; q++) {
            int eq = 4*q + lhi;
            int de = __shfl(dstP, eq), se = __shfl(srcP, eq);
            ug[q] = *(const bf16x8*)(UU + (size_t)de*256 + l15*8);
            vg[q] = *(const bf16x8*)(UU + (size_t)se*256 + 128 + l15*8);
        }

        // --- cvt first half (ar00/01 rotated: ready long ago) ---
        bf16x8 A[2];
        pack8v(A[0], ar00, ar01);

        // --- fire NEXT iter's first-half attr loads (rotated pipeline) ---
        int e0n = e0 + STRIDE;
        int eb = (e0n < NE) ? e0n : 0;
        {
            const float* pn = attr + (size_t)(eb + l15)*64 + lhi*8;
            ar00 = ntload4(pn); ar01 = ntload4(pn + 4);
        }

        // --- cvt second half (ar10/11 issued at END of previous iter) ---
        pack8v(A[1], ar10, ar11);

        // --- MFMA block (gathers + next-attr stay in flight) ---
        #pragma unroll
        for (int t = 0; t < 10; t++) {
            f32x4 acc = {0.f, 0.f, 0.f, 0.f};
            acc = __builtin_amdgcn_mfma_f32_16x16x32_bf16(A[0], B[t][0], acc, 0, 0, 0);
            acc = __builtin_amdgcn_mfma_f32_16x16x32_bf16(A[1], B[t][1], acc, 0, 0, 0);
            int col = t*16 + l15;
            float bias = BC2[col];
            if (t < 2) {
                #pragma unroll
                for (int r = 0; r < 4; r++) {
                    int er = e0 + lhi*4 + r;
                    __builtin_nontemporal_store(acc[r] + bias,
                                                edge_out + (size_t)er*32 + col);
                }
            } else {
                int hc = col - 32;                 // 0..127
                #pragma unroll
                for (int r = 0; r < 4; r++)
                    vw[(lhi*4 + r)*136 + hc] = f2bf(acc[r] + bias);
            }
        }

        // --- phase 2: per q, edge eq = 4q+lhi, this lane covers 8 a-values ---
        #pragma unroll
        for (int q = 0; q < 4; q++) {
            int eq = 4*q + lhi;
            bf16x8 vv = *(const bf16x8*)(vw + eq*136 + l15*8);
            float part = 0.f;
            #pragma unroll
            for (int j = 0; j < 8; j++) {
                float s = bf2f((u16)vv[j]) + bf2f((u16)ug[q][j]) + bf2f((u16)vg[q][j]);
                s = fmaxf(s, 0.2f * s);            // leaky relu
                part = fmaf(s, att_c[j], part);
            }
            part += __shfl_xor(part, 1);
            part += __shfl_xor(part, 2);
            part += __shfl_xor(part, 4);           // lane c=0: head0, c=8: head1
            float a1 = __shfl_xor(part, 8);        // c=0 receives head1
            int pos = __shfl(dstP, eq)*BUCKET + __shfl(posP, eq);
            int srcE = __shfl(srcP, eq);
            if (l15 == 0) {
                f16x2 h = __builtin_amdgcn_cvt_pkrtz(part, a1);
                aw[pos] = make_int2(__builtin_bit_cast(int, h), srcE);
            }
        }

        // --- epilogue: ei prefetch + SECOND-half attr loads for next iter ---
        if (l < 16) { srcP = ei[eb + l]; dstP = ei[NE + eb + l]; }
        {
            const float* pn = attr + (size_t)(eb + l15)*64 + lhi*8;
            ar10 = ntload4(pn + 32); ar11 = ntload4(pn + 36);
        }
    }
}

// ---------------------------------------------------------------------------
// K4: 1 wave per node, lane-structured MAX-FREE softmax aggregation, UNROLLED
// x2: 8 edges (2 aw loads + 2 XL row gathers per lane) in flight per round.
// ---------------------------------------------------------------------------
__global__ __launch_bounds__(256) void k_agg(const u16* __restrict__ XL,
                                             const int2* __restrict__ aw,
                                             const int* __restrict__ curs,
                                             u16* __restrict__ out128) {
    const int w = threadIdx.x >> 6, l = threadIdx.x & 63;
    const int lhi = l >> 4, l15 = l & 15;
    const bool head1 = (l15 >= 8);
    for (int n = blockIdx.x * 4 + w; n < NN; n += gridDim.x * 4) {
        int d = curs[n];
        const int2* base = aw + (size_t)n * BUCKET;
        float sA = 0.f, sB = 0.f;
        float acc[8] = {0.f,0.f,0.f,0.f,0.f,0.f,0.f,0.f};
        int cap = (d > 0) ? (d - 1) : 0;
        for (int j0 = 0; j0 < d; j0 += 8) {
            int j1 = j0 + lhi, j2 = j0 + 4 + lhi;
            bool ok1 = j1 < d, ok2 = j2 < d;
            int2 q1 = base[min(j1, cap)];
            int2 q2 = base[min(j2, cap)];
            int s1 = min(max(q1.y, 0), NN - 1);
            int s2 = min(max(q2.y, 0), NN - 1);
            bf16x8 xr1 = *(const bf16x8*)(XL + (size_t)s1*128 + l15*8);
            bf16x8 xr2 = *(const bf16x8*)(XL + (size_t)s2*128 + l15*8);
            f16x2 h1 = __builtin_bit_cast(f16x2, q1.x);
            f16x2 h2 = __builtin_bit_cast(f16x2, q2.x);
            float e10 = ok1 ? __expf((float)h1[0]) : 0.f;
            float e11 = ok1 ? __expf((float)h1[1]) : 0.f;
            float e20 = ok2 ? __expf((float)h2[0]) : 0.f;
            float e21 = ok2 ? __expf((float)h2[1]) : 0.f;
            sA += e10 + e20; sB += e11 + e21;
            float w1 = head1 ? e11 : e10;
            float w2 = head1 ? e21 : e20;
            #pragma unroll
            for (int k = 0; k < 8; k++) {
                acc[k] = fmaf(w1, bf2f((u16)xr1[k]), acc[k]);
                acc[k] = fmaf(w2, bf2f((u16)xr2[k]), acc[k]);
            }
        }
        // reduce partials across the 4 lhi groups
        sA += __shfl_xor(sA, 16); sA += __shfl_xor(sA, 32);
        sB += __shfl_xor(sB, 16); sB += __shfl_xor(sB, 32);
        #pragma unroll
        for (int k = 0; k < 8; k++) {
            acc[k] += __shfl_xor(acc[k], 16);
            acc[k] += __shfl_xor(acc[k], 32);
        }
        float inv = 1.f / ((head1 ? sB : sA) + 1e-16f);
        bf16x8 o;
        #pragma unroll
        for (int k = 0; k < 8; k++) o[k] = (short)f2bf(acc[k] * inv);
        if (lhi == 0)
            *(bf16x8*)(out128 + (size_t)n*128 + l15*8) = o;
    }
}

// ---------------------------------------------------------------------------
// K5: node_out[N,64] = out128[N,128](bf16) @ W_nout + b_nout   (MFMA)
// ---------------------------------------------------------------------------
__global__ __launch_bounds__(256) void k_proj(const u16* __restrict__ out128,
                                              const float* __restrict__ Wn,
                                              const float* __restrict__ bn,
                                              float* __restrict__ node_out) {
    const int w = threadIdx.x >> 6, l = threadIdx.x & 63;
    const int l15 = l & 15, lhi = l >> 4;

    bf16x8 B[4][4];
    #pragma unroll
    for (int t = 0; t < 4; t++) {
        int col = t*16 + l15;
        #pragma unroll
        for (int ks = 0; ks < 4; ks++) {
            #pragma unroll
            for (int j = 0; j < 8; j++) {
                int k = ks*32 + lhi*8 + j;
                B[t][ks][j] = (short)f2bf(Wn[k*64 + col]);
            }
        }
    }

    int nb = blockIdx.x * 64;
    int row = nb + 16*w + l15;
    int rowc = row < NN ? row : NN - 1;
    bf16x8 A[4];
    #pragma unroll
    for (int ks = 0; ks < 4; ks++)
        A[ks] = *(const bf16x8*)(out128 + (size_t)rowc*128 + ks*32 + lhi*8);
    #pragma unroll
    for (int t = 0; t < 4; t++) {
        f32x4 acc = {0.f, 0.f, 0.f, 0.f};
        #pragma unroll
        for (int ks = 0; ks < 4; ks++)
            acc = __builtin_amdgcn_mfma_f32_16x16x32_bf16(A[ks], B[t][ks], acc, 0, 0, 0);
        int col = t*16 + l15;
        float bias = bn[col];
        #pragma unroll
        for (int r = 0; r < 4; r++) {
            int node = nb + 16*w + lhi*4 + r;
            if (node < NN)
                __builtin_nontemporal_store(acc[r] + bias,
                                            node_out + (size_t)node*64 + col);
        }
    }
}

// ---------------------------------------------------------------------------
extern "C" void kernel_launch(void* const* d_in, const int* in_sizes, int n_in,
                              void* d_out, int out_size, void* d_ws, size_t ws_size,
                              hipStream_t stream) {
    const float* x         = (const float*)d_in[0];
    const float* edge_attr = (const float*)d_in[1];
    const int*   ei        = (const int*)  d_in[2];
    const float* Wl        = (const float*)d_in[3];
    const float* bl        = (const float*)d_in[4];
    const float* We        = (const float*)d_in[5];
    const float* be        = (const float*)d_in[6];
    const float* W_att     = (const float*)d_in[7];
    const float* b_att     = (const float*)d_in[8];
    const float* att       = (const float*)d_in[9];
    const float* W_nout    = (const float*)d_in[10];
    const float* b_nout    = (const float*)d_in[11];
    const float* W_eout    = (const float*)d_in[12];
    const float* b_eout    = (const float*)d_in[13];

    float* node_out = (float*)d_out;                 // [N,64]
    float* edge_out = node_out + (size_t)NN * 64;    // [E,32]

    char* p = (char*)d_ws;
    u16* XL      = (u16*)p;            p += (size_t)NN * 128 * 2;   // bf16 [N,128]
    u16* UU      = (u16*)p;            p += (size_t)NN * 256 * 2;   // bf16 [N,256]
    u16* out128  = (u16*)p;            p += (size_t)NN * 128 * 2;   // bf16 [N,128]
    int2* aw     = (int2*)p;           p += (size_t)NN * BUCKET * 8; // bucketed {f16 a0,a1|src}
    float* WC1   = (float*)p;          p += 128 * 384 * 4;
    float* BC1   = (float*)p;          p += 384 * 4;
    float* WC2   = (float*)p;          p += 64 * 160 * 4;
    float* BC2   = (float*)p;          p += 160 * 4;
    u16*  WC2b   = (u16*)p;            p += 10240 * 2;              // packed B frags
    int*   curs  = (int*)p;            p += NN * 4;

    hipMemsetAsync(curs, 0, NN * sizeof(int), stream);

    k_prep<<<(PREP_TOT + 255) / 256, 256, 0, stream>>>(Wl, bl, We, be, W_att, b_att,
                                                       W_eout, b_eout, WC1, BC1, WC2, BC2);
    k_prep2<<<40, 256, 0, stream>>>(WC2, WC2b);
    k_node<<<1563, 256, 0, stream>>>(x, WC1, BC1, XL, UU);
    k_edge<<<5120, 256, 0, stream>>>(edge_attr, ei, UU, WC2b, BC2, att,
                                     edge_out, curs, aw);
    k_agg<<<2048, 256, 0, stream>>>(XL, aw, curs, out128);
    k_proj<<<(NN + 63) / 64, 256, 0, stream>>>(out128, W_nout, b_nout, node_out);
}

// Round 23
// 355.585 us; speedup vs baseline: 1.1387x; 1.1387x over previous
//
#include <hip/hip_runtime.h>
#include <hip/hip_bf16.h>

#define NN 50000
#define NE 1600000
#define BUCKET 128   // aw slots per node; degree ~ Poisson(32), max ~70 << 128

typedef float f32x4 __attribute__((ext_vector_type(4)));
typedef short bf16x8 __attribute__((ext_vector_type(8)));
typedef __fp16 f16x2 __attribute__((ext_vector_type(2)));
typedef unsigned short u16;

// bf16 convert via HIP intrinsic (RNE).
__device__ inline u16 f2bf(float f) {
    union { __hip_bfloat16 h; u16 u; } c;
    c.h = __float2bfloat16(f);
    return c.u;
}
__device__ inline float bf2f(u16 u) {
    union { unsigned u; float f; } v; v.u = ((unsigned)u) << 16; return v.f;
}
__device__ inline void pack8v(bf16x8& d, f32x4 p0, f32x4 p1) {
    d[0]=(short)f2bf(p0[0]); d[1]=(short)f2bf(p0[1]); d[2]=(short)f2bf(p0[2]); d[3]=(short)f2bf(p0[3]);
    d[4]=(short)f2bf(p1[0]); d[5]=(short)f2bf(p1[1]); d[6]=(short)f2bf(p1[2]); d[7]=(short)f2bf(p1[3]);
}
// nt for streamed-once data only (attr, edge_out, node_out, x).
__device__ inline f32x4 ntload4(const float* p) {
    return __builtin_nontemporal_load((const f32x4*)p);
}

// ---------------------------------------------------------------------------
// K0: fold weights.
// ---------------------------------------------------------------------------
#define PREP_TOT (128*384 + 384 + 64*160 + 160)

__global__ void k_prep(const float* __restrict__ Wl, const float* __restrict__ bl,
                       const float* __restrict__ We, const float* __restrict__ be,
                       const float* __restrict__ W_att, const float* __restrict__ b_att,
                       const float* __restrict__ W_eout, const float* __restrict__ b_eout,
                       float* __restrict__ WC1, float* __restrict__ BC1,
                       float* __restrict__ WC2, float* __restrict__ BC2) {
    int id = blockIdx.x * blockDim.x + threadIdx.x;
    if (id < 128*384) {
        int k = id / 384, col = id % 384;
        float v;
        if (col < 128) v = Wl[k*128 + col];
        else {
            int role = (col - 128) >> 7;          // 0 = u_i(dst), 1 = u_j(src)
            int hc = (col - 128) & 127, h = hc >> 6, a = hc & 63;
            float s = 0.f;
            for (int c = 0; c < 64; c++) s += Wl[k*128 + h*64 + c] * W_att[(role*64 + c)*64 + a];
            v = s;
        }
        WC1[id] = v;
    } else if (id < 128*384 + 384) {
        int col = id - 128*384;
        float v;
        if (col < 128) v = bl[col];
        else {
            int role = (col - 128) >> 7;
            int hc = (col - 128) & 127, h = hc >> 6, a = hc & 63;
            float s = 0.f;
            for (int c = 0; c < 64; c++) s += bl[h*64 + c] * W_att[(role*64 + c)*64 + a];
            v = s;
        }
        BC1[col] = v;
    } else if (id < 128*384 + 384 + 64*160) {
        int id2 = id - (128*384 + 384);
        int k = id2 / 160, col = id2 % 160;
        float s = 0.f;
        if (col < 32) { for (int m = 0; m < 64; m++) s += We[k*64 + m] * W_eout[m*32 + col]; }
        else {
            int hc = col - 32, h = hc >> 6, a = hc & 63;
            for (int j = 0; j < 32; j++) s += We[k*64 + h*32 + j] * W_att[(128 + j)*64 + a];
        }
        WC2[id2] = s;
    } else if (id < PREP_TOT) {
        int col = id - (128*384 + 384 + 64*160);
        float s = 0.f;
        if (col < 32) { for (int m = 0; m < 64; m++) s += be[m] * W_eout[m*32 + col]; s += b_eout[col]; }
        else {
            int hc = col - 32, h = hc >> 6, a = hc & 63;
            for (int j = 0; j < 32; j++) s += be[h*32 + j] * W_att[(128 + j)*64 + a];
            s += b_att[a];
        }
        BC2[col] = s;
    }
}

// K0b: pre-pack WC2 into per-lane bf16 MFMA B-fragments.
__global__ void k_prep2(const float* __restrict__ WC2, u16* __restrict__ WC2b) {
    int id = blockIdx.x * blockDim.x + threadIdx.x;
    if (id < 10240) {
        int j = id & 7, l = (id >> 3) & 63, ks = (id >> 9) & 1, t = id >> 10;
        int col = t*16 + (l & 15);
        int k = ks*32 + (l >> 4)*8 + j;
        WC2b[id] = f2bf(WC2[k*160 + col]);
    }
}

// ---------------------------------------------------------------------------
// K1: node transform -> XL[N,128] bf16 (xl) and UU[N,256] bf16 (u_i|u_j).
// ---------------------------------------------------------------------------
__global__ __launch_bounds__(256) void k_node(const float* __restrict__ x,
                                              const float* __restrict__ WC1,
                                              const float* __restrict__ BC1,
                                              u16* __restrict__ XL,
                                              u16* __restrict__ UU) {
    const int w = threadIdx.x >> 6, l = threadIdx.x & 63;
    const int l15 = l & 15, lhi = l >> 4;

    bf16x8 B[6][4];
    #pragma unroll
    for (int t = 0; t < 6; t++) {
        int col = (6*w + t)*16 + l15;
        #pragma unroll
        for (int ks = 0; ks < 4; ks++) {
            #pragma unroll
            for (int j = 0; j < 8; j++) {
                int k = ks*32 + lhi*8 + j;
                B[t][ks][j] = (short)f2bf(WC1[k*384 + col]);
            }
        }
    }

    for (int nb = blockIdx.x * 16; nb < NN; nb += gridDim.x * 16) {
        int row = nb + l15;
        bf16x8 A[4];
        #pragma unroll
        for (int ks = 0; ks < 4; ks++) {
            const float* p = x + (size_t)row*128 + ks*32 + lhi*8;
            pack8v(A[ks], ntload4(p), ntload4(p + 4));
        }
        #pragma unroll
        for (int t = 0; t < 6; t++) {
            f32x4 acc = {0.f, 0.f, 0.f, 0.f};
            #pragma unroll
            for (int ks = 0; ks < 4; ks++)
                acc = __builtin_amdgcn_mfma_f32_16x16x32_bf16(A[ks], B[t][ks], acc, 0, 0, 0);
            int col = (6*w + t)*16 + l15;
            float bias = BC1[col];
            #pragma unroll
            for (int r = 0; r < 4; r++) {
                int node = nb + lhi*4 + r;
                float v = acc[r] + bias;
                if (col < 128) XL[(size_t)node*128 + col] = f2bf(v);
                else           UU[(size_t)node*256 + (col - 128)] = f2bf(v);
            }
        }
    }
}

// ---------------------------------------------------------------------------
// K2: wave-autonomous edge kernel, rotated attr pipeline, ei prefetch at END
// of loop body.  (R19/R21 configuration — measured best: k_edge 248us.)
// Register wall: VGPR sticky at 104 (4 waves/SIMD) under all 6 source-level
// shave attempts; grid 1024 = exact 4-blocks/CU fit.
// NOTE: plain launch_bounds(256) — min-waves bound spills B (R6).
// ---------------------------------------------------------------------------
__global__ __launch_bounds__(256) void k_edge(const float* __restrict__ attr,
                                              const int* __restrict__ ei,
                                              const u16* __restrict__ UU,
                                              const u16* __restrict__ WC2b,
                                              const float* __restrict__ BC2,
                                              const float* __restrict__ att,
                                              float* __restrict__ edge_out,
                                              int* __restrict__ curs,
                                              int2* __restrict__ aw) {
    __shared__ u16 vlds[4][16 * 136];
    const int tid = threadIdx.x;
    const int w = tid >> 6, l = tid & 63, l15 = l & 15, lhi = l >> 4;

    bf16x8 B[10][2];
    #pragma unroll
    for (int t = 0; t < 10; t++)
        #pragma unroll
        for (int ks = 0; ks < 2; ks++)
            B[t][ks] = *(const bf16x8*)(WC2b + (size_t)((t*2 + ks)*64 + l)*8);

    // per-lane attention weights for chunk c=l15 (head = c>>3)
    float att_c[8];
    {
        int base = (l15 >> 3)*64 + (l15 & 7)*8;
        f32x4 t0 = *(const f32x4*)(att + base);
        f32x4 t1 = *(const f32x4*)(att + base + 4);
        att_c[0]=t0[0]; att_c[1]=t0[1]; att_c[2]=t0[2]; att_c[3]=t0[3];
        att_c[4]=t1[0]; att_c[5]=t1[1]; att_c[6]=t1[2]; att_c[7]=t1[3];
    }

    u16* vw = vlds[w];
    const int STRIDE = gridDim.x * 64;
    int e0 = (blockIdx.x*4 + w)*16;
    int srcP = 0, dstP = 0;
    if (l < 16) { srcP = ei[e0 + l]; dstP = ei[NE + e0 + l]; }
    // prologue: prefetch iter-0 attr
    f32x4 ar00, ar01, ar10, ar11;
    {
        const float* pa = attr + (size_t)(e0 + l15)*64 + lhi*8;
        ar00 = ntload4(pa); ar01 = ntload4(pa + 4);
        ar10 = ntload4(pa + 32); ar11 = ntload4(pa + 36);
    }

    for (; e0 < NE; e0 += STRIDE) {
        // --- bucket slot (result consumed in phase 2) ---
        int posP = 0;
        if (l < 16) posP = atomicAdd(curs + dstP, 1);

        // --- coalesced UU gathers: lane = (edge 4q+lhi, chunk l15); CACHED ---
        bf16x8 ug[4], vg[4];
        #pragma unroll
        for (int q = 0; q < 4; q++) {
            int eq = 4*q + lhi;
            int de = __shfl(dstP, eq), se = __shfl(srcP, eq);
            ug[q] = *(const bf16x8*)(UU + (size_t)de*256 + l15*8);
            vg[q] = *(const bf16x8*)(UU + (size_t)se*256 + 128 + l15*8);
        }

        // --- cvt consumes previously-loaded attr (waits only on old ar) ---
        bf16x8 A[2];
        pack8v(A[0], ar00, ar01);
        pack8v(A[1], ar10, ar11);

        // --- fire NEXT iter's attr loads before MFMA (rotated pipeline) ---
        int e0n = e0 + STRIDE;
        int eb = (e0n < NE) ? e0n : 0;
        {
            const float* pn = attr + (size_t)(eb + l15)*64 + lhi*8;
            ar00 = ntload4(pn); ar01 = ntload4(pn + 4);
            ar10 = ntload4(pn + 32); ar11 = ntload4(pn + 36);
        }

        // --- MFMA block (gathers + next-attr stay in flight) ---
        #pragma unroll
        for (int t = 0; t < 10; t++) {
            f32x4 acc = {0.f, 0.f, 0.f, 0.f};
            acc = __builtin_amdgcn_mfma_f32_16x16x32_bf16(A[0], B[t][0], acc, 0, 0, 0);
            acc = __builtin_amdgcn_mfma_f32_16x16x32_bf16(A[1], B[t][1], acc, 0, 0, 0);
            int col = t*16 + l15;
            float bias = BC2[col];
            if (t < 2) {
                #pragma unroll
                for (int r = 0; r < 4; r++) {
                    int er = e0 + lhi*4 + r;
                    __builtin_nontemporal_store(acc[r] + bias,
                                                edge_out + (size_t)er*32 + col);
                }
            } else {
                int hc = col - 32;                 // 0..127
                #pragma unroll
                for (int r = 0; r < 4; r++)
                    vw[(lhi*4 + r)*136 + hc] = f2bf(acc[r] + bias);
            }
        }

        // --- phase 2: per q, edge eq = 4q+lhi, this lane covers 8 a-values ---
        #pragma unroll
        for (int q = 0; q < 4; q++) {
            int eq = 4*q + lhi;
            bf16x8 vv = *(const bf16x8*)(vw + eq*136 + l15*8);
            float part = 0.f;
            #pragma unroll
            for (int j = 0; j < 8; j++) {
                float s = bf2f((u16)vv[j]) + bf2f((u16)ug[q][j]) + bf2f((u16)vg[q][j]);
                s = fmaxf(s, 0.2f * s);            // leaky relu
                part = fmaf(s, att_c[j], part);
            }
            part += __shfl_xor(part, 1);
            part += __shfl_xor(part, 2);
            part += __shfl_xor(part, 4);           // lane c=0: head0, c=8: head1
            float a1 = __shfl_xor(part, 8);        // c=0 receives head1
            int pos = __shfl(dstP, eq)*BUCKET + __shfl(posP, eq);
            int srcE = __shfl(srcP, eq);
            if (l15 == 0) {
                f16x2 h = __builtin_amdgcn_cvt_pkrtz(part, a1);
                aw[pos] = make_int2(__builtin_bit_cast(int, h), srcE);
            }
        }

        // --- ei prefetch for next iter (post-phase2: no copies needed) ---
        if (l < 16) { srcP = ei[eb + l]; dstP = ei[NE + eb + l]; }
    }
}

// ---------------------------------------------------------------------------
// K4: 1 wave per node, lane-structured MAX-FREE softmax aggregation, UNROLLED
// x2: 8 edges (2 aw loads + 2 XL row gathers per lane) in flight per round.
// ---------------------------------------------------------------------------
__global__ __launch_bounds__(256) void k_agg(const u16* __restrict__ XL,
                                             const int2* __restrict__ aw,
                                             const int* __restrict__ curs,
                                             u16* __restrict__ out128) {
    const int w = threadIdx.x >> 6, l = threadIdx.x & 63;
    const int lhi = l >> 4, l15 = l & 15;
    const bool head1 = (l15 >= 8);
    for (int n = blockIdx.x * 4 + w; n < NN; n += gridDim.x * 4) {
        int d = curs[n];
        const int2* base = aw + (size_t)n * BUCKET;
        float sA = 0.f, sB = 0.f;
        float acc[8] = {0.f,0.f,0.f,0.f,0.f,0.f,0.f,0.f};
        int cap = (d > 0) ? (d - 1) : 0;
        for (int j0 = 0; j0 < d; j0 += 8) {
            int j1 = j0 + lhi, j2 = j0 + 4 + lhi;
            bool ok1 = j1 < d, ok2 = j2 < d;
            int2 q1 = base[min(j1, cap)];
            int2 q2 = base[min(j2, cap)];
            int s1 = min(max(q1.y, 0), NN - 1);
            int s2 = min(max(q2.y, 0), NN - 1);
            bf16x8 xr1 = *(const bf16x8*)(XL + (size_t)s1*128 + l15*8);
            bf16x8 xr2 = *(const bf16x8*)(XL + (size_t)s2*128 + l15*8);
            f16x2 h1 = __builtin_bit_cast(f16x2, q1.x);
            f16x2 h2 = __builtin_bit_cast(f16x2, q2.x);
            float e10 = ok1 ? __expf((float)h1[0]) : 0.f;
            float e11 = ok1 ? __expf((float)h1[1]) : 0.f;
            float e20 = ok2 ? __expf((float)h2[0]) : 0.f;
            float e21 = ok2 ? __expf((float)h2[1]) : 0.f;
            sA += e10 + e20; sB += e11 + e21;
            float w1 = head1 ? e11 : e10;
            float w2 = head1 ? e21 : e20;
            #pragma unroll
            for (int k = 0; k < 8; k++) {
                acc[k] = fmaf(w1, bf2f((u16)xr1[k]), acc[k]);
                acc[k] = fmaf(w2, bf2f((u16)xr2[k]), acc[k]);
            }
        }
        // reduce partials across the 4 lhi groups
        sA += __shfl_xor(sA, 16); sA += __shfl_xor(sA, 32);
        sB += __shfl_xor(sB, 16); sB += __shfl_xor(sB, 32);
        #pragma unroll
        for (int k = 0; k < 8; k++) {
            acc[k] += __shfl_xor(acc[k], 16);
            acc[k] += __shfl_xor(acc[k], 32);
        }
        float inv = 1.f / ((head1 ? sB : sA) + 1e-16f);
        bf16x8 o;
        #pragma unroll
        for (int k = 0; k < 8; k++) o[k] = (short)f2bf(acc[k] * inv);
        if (lhi == 0)
            *(bf16x8*)(out128 + (size_t)n*128 + l15*8) = o;
    }
}

// ---------------------------------------------------------------------------
// K5: node_out[N,64] = out128[N,128](bf16) @ W_nout + b_nout   (MFMA)
// ---------------------------------------------------------------------------
__global__ __launch_bounds__(256) void k_proj(const u16* __restrict__ out128,
                                              const float* __restrict__ Wn,
                                              const float* __restrict__ bn,
                                              float* __restrict__ node_out) {
    const int w = threadIdx.x >> 6, l = threadIdx.x & 63;
    const int l15 = l & 15, lhi = l >> 4;

    bf16x8 B[4][4];
    #pragma unroll
    for (int t = 0; t < 4; t++) {
        int col = t*16 + l15;
        #pragma unroll
        for (int ks = 0; ks < 4; ks++) {
            #pragma unroll
            for (int j = 0; j < 8; j++) {
                int k = ks*32 + lhi*8 + j;
                B[t][ks][j] = (short)f2bf(Wn[k*64 + col]);
            }
        }
    }

    int nb = blockIdx.x * 64;
    int row = nb + 16*w + l15;
    int rowc = row < NN ? row : NN - 1;
    bf16x8 A[4];
    #pragma unroll
    for (int ks = 0; ks < 4; ks++)
        A[ks] = *(const bf16x8*)(out128 + (size_t)rowc*128 + ks*32 + lhi*8);
    #pragma unroll
    for (int t = 0; t < 4; t++) {
        f32x4 acc = {0.f, 0.f, 0.f, 0.f};
        #pragma unroll
        for (int ks = 0; ks < 4; ks++)
            acc = __builtin_amdgcn_mfma_f32_16x16x32_bf16(A[ks], B[t][ks], acc, 0, 0, 0);
        int col = t*16 + l15;
        float bias = bn[col];
        #pragma unroll
        for (int r = 0; r < 4; r++) {
            int node = nb + 16*w + lhi*4 + r;
            if (node < NN)
                __builtin_nontemporal_store(acc[r] + bias,
                                            node_out + (size_t)node*64 + col);
        }
    }
}

// ---------------------------------------------------------------------------
extern "C" void kernel_launch(void* const* d_in, const int* in_sizes, int n_in,
                              void* d_out, int out_size, void* d_ws, size_t ws_size,
                              hipStream_t stream) {
    const float* x         = (const float*)d_in[0];
    const float* edge_attr = (const float*)d_in[1];
    const int*   ei        = (const int*)  d_in[2];
    const float* Wl        = (const float*)d_in[3];
    const float* bl        = (const float*)d_in[4];
    const float* We        = (const float*)d_in[5];
    const float* be        = (const float*)d_in[6];
    const float* W_att     = (const float*)d_in[7];
    const float* b_att     = (const float*)d_in[8];
    const float* att       = (const float*)d_in[9];
    const float* W_nout    = (const float*)d_in[10];
    const float* b_nout    = (const float*)d_in[11];
    const float* W_eout    = (const float*)d_in[12];
    const float* b_eout    = (const float*)d_in[13];

    float* node_out = (float*)d_out;                 // [N,64]
    float* edge_out = node_out + (size_t)NN * 64;    // [E,32]

    char* p = (char*)d_ws;
    u16* XL      = (u16*)p;            p += (size_t)NN * 128 * 2;   // bf16 [N,128]
    u16* UU      = (u16*)p;            p += (size_t)NN * 256 * 2;   // bf16 [N,256]
    u16* out128  = (u16*)p;            p += (size_t)NN * 128 * 2;   // bf16 [N,128]
    int2* aw     = (int2*)p;           p += (size_t)NN * BUCKET * 8; // bucketed {f16 a0,a1|src}
    float* WC1   = (float*)p;          p += 128 * 384 * 4;
    float* BC1   = (float*)p;          p += 384 * 4;
    float* WC2   = (float*)p;          p += 64 * 160 * 4;
    float* BC2   = (float*)p;          p += 160 * 4;
    u16*  WC2b   = (u16*)p;            p += 10240 * 2;              // packed B frags
    int*   curs  = (int*)p;            p += NN * 4;

    hipMemsetAsync(curs, 0, NN * sizeof(int), stream);

    k_prep<<<(PREP_TOT + 255) / 256, 256, 0, stream>>>(Wl, bl, We, be, W_att, b_att,
                                                       W_eout, b_eout, WC1, BC1, WC2, BC2);
    k_prep2<<<40, 256, 0, stream>>>(WC2, WC2b);
    k_node<<<1563, 256, 0, stream>>>(x, WC1, BC1, XL, UU);
    k_edge<<<1024, 256, 0, stream>>>(edge_attr, ei, UU, WC2b, BC2, att,
                                     edge_out, curs, aw);
    k_agg<<<2048, 256, 0, stream>>>(XL, aw, curs, out128);
    k_proj<<<(NN + 63) / 64, 256, 0, stream>>>(out128, W_nout, b_nout, node_out);
}